// Round 2
// baseline (1097.781 us; speedup 1.0000x reference)
//
#include <hip/hip_runtime.h>
#include <hip/hip_bf16.h>

typedef __attribute__((ext_vector_type(8))) short bf16x8_t;
typedef __attribute__((ext_vector_type(4))) float f32x4_t;

__device__ __forceinline__ float bf2f(unsigned int u16) {
    union { unsigned int i; float f; } c;
    c.i = (u16 & 0xffffu) << 16;
    return c.f;
}
__device__ __forceinline__ unsigned short f2bf(float f) {
    union { float f; unsigned int i; } c; c.f = f;
    unsigned int x = c.i;
    unsigned int r = (x + 0x7fffu + ((x >> 16) & 1u)) >> 16;
    return (unsigned short)r;
}

// ---------------- cast kernels ----------------

// x f32 -> hi bf16 + lo bf16 (residual)
__global__ void cast_x_split_kernel(const float* __restrict__ in,
                                    unsigned short* __restrict__ hi,
                                    unsigned short* __restrict__ lo, int n4) {
    int i = blockIdx.x * blockDim.x + threadIdx.x;
    int stride = gridDim.x * blockDim.x;
    for (; i < n4; i += stride) {
        float4 v = *(const float4*)(in + (size_t)i * 4);
        ushort4 h, l;
        h.x = f2bf(v.x); l.x = f2bf(v.x - bf2f(h.x));
        h.y = f2bf(v.y); l.y = f2bf(v.y - bf2f(h.y));
        h.z = f2bf(v.z); l.z = f2bf(v.z - bf2f(h.z));
        h.w = f2bf(v.w); l.w = f2bf(v.w - bf2f(h.w));
        *(ushort4*)(hi + (size_t)i * 4) = h;
        *(ushort4*)(lo + (size_t)i * 4) = l;
    }
}

// W [K][N] f32 -> Wt [N][K] bf16 (plain, for gate MLP weights)
__global__ __launch_bounds__(256) void cast_wt_kernel(const float* __restrict__ W,
                                                      unsigned short* __restrict__ Wt,
                                                      int K, int N) {
    __shared__ unsigned short tile[32][33];
    int c0 = blockIdx.x * 32, k0 = blockIdx.y * 32;
    int tx = threadIdx.x & 31, ty = threadIdx.x >> 5;  // 32 x 8
#pragma unroll
    for (int i = 0; i < 4; ++i) {
        int k = k0 + ty + i * 8;
        tile[ty + i * 8][tx] = f2bf(W[(size_t)k * N + c0 + tx]);
    }
    __syncthreads();
#pragma unroll
    for (int i = 0; i < 4; ++i) {
        int c = c0 + ty + i * 8;
        Wt[(size_t)c * K + k0 + tx] = tile[tx][ty + i * 8];
    }
}

// W [K][N] f32 -> Wt [N][K] bf16 hi + lo (split, for kv weights)
__global__ __launch_bounds__(256) void cast_wt_split_kernel(const float* __restrict__ W,
                                                            unsigned short* __restrict__ Wh,
                                                            unsigned short* __restrict__ Wl,
                                                            int K, int N) {
    __shared__ unsigned short th[32][33];
    __shared__ unsigned short tl[32][33];
    int c0 = blockIdx.x * 32, k0 = blockIdx.y * 32;
    int tx = threadIdx.x & 31, ty = threadIdx.x >> 5;
#pragma unroll
    for (int i = 0; i < 4; ++i) {
        int k = k0 + ty + i * 8;
        float f = W[(size_t)k * N + c0 + tx];
        unsigned short h = f2bf(f);
        th[ty + i * 8][tx] = h;
        tl[ty + i * 8][tx] = f2bf(f - bf2f(h));
    }
    __syncthreads();
#pragma unroll
    for (int i = 0; i < 4; ++i) {
        int c = c0 + ty + i * 8;
        Wt_write:;
        Wh[(size_t)c * K + k0 + tx] = th[tx][ty + i * 8];
        Wl[(size_t)c * K + k0 + tx] = tl[tx][ty + i * 8];
    }
}

// ---------------- gate-MLP bf16 MFMA GEMM, 128x128x32 tile ----------------
// A: [M][K] bf16, Bt: [N][K] bf16. EPI 0: bias+relu -> bf16. EPI 1: bias+sigmoid -> f32.
template <int EPI>
__global__ __launch_bounds__(256, 2) void gemm_gate_kernel(
    const unsigned short* __restrict__ A,
    const unsigned short* __restrict__ Bt,
    const float* __restrict__ bias,
    unsigned short* __restrict__ out_bf,
    float* __restrict__ out_f,
    int M, int N, int K)
{
    __shared__ unsigned short As[128][32];
    __shared__ unsigned short Bs[128][32];
    int t = threadIdx.x;
    int lane = t & 63, w = t >> 6;
    int wm = w >> 1, wn = w & 1;
    int row0 = blockIdx.x * 128;
    int col0 = blockIdx.y * 128;

    f32x4_t acc[4][4];
#pragma unroll
    for (int i = 0; i < 4; ++i)
#pragma unroll
        for (int j = 0; j < 4; ++j) acc[i][j] = (f32x4_t)(0.0f);

    const unsigned short* Abase = A + (size_t)row0 * K;
    const unsigned short* Bbase = Bt + (size_t)col0 * K;

    for (int k0 = 0; k0 < K; k0 += 32) {
#pragma unroll
        for (int s = 0; s < 2; ++s) {
            int c = t + s * 256;
            int r = c >> 2, o8 = (c & 3) * 8;
            *(int4*)(&As[r][o8]) = *(const int4*)(Abase + (size_t)r * K + k0 + o8);
            *(int4*)(&Bs[r][o8]) = *(const int4*)(Bbase + (size_t)r * K + k0 + o8);
        }
        __syncthreads();
        int kq = (lane >> 4) * 8;
        int mrow = wm * 64 + (lane & 15);
        int ncol = wn * 64 + (lane & 15);
        bf16x8_t af[4], bfr[4];
#pragma unroll
        for (int i = 0; i < 4; ++i) af[i] = *(const bf16x8_t*)(&As[mrow + i * 16][kq]);
#pragma unroll
        for (int j = 0; j < 4; ++j) bfr[j] = *(const bf16x8_t*)(&Bs[ncol + j * 16][kq]);
#pragma unroll
        for (int i = 0; i < 4; ++i)
#pragma unroll
            for (int j = 0; j < 4; ++j)
                acc[i][j] = __builtin_amdgcn_mfma_f32_16x16x32_bf16(af[i], bfr[j], acc[i][j], 0, 0, 0);
        __syncthreads();
    }

    int rbase = row0 + wm * 64 + ((lane >> 4) << 2);
    int cbase = col0 + wn * 64 + (lane & 15);
#pragma unroll
    for (int i = 0; i < 4; ++i) {
#pragma unroll
        for (int j = 0; j < 4; ++j) {
            int col = cbase + j * 16;
            float b = bias[col];
#pragma unroll
            for (int r = 0; r < 4; ++r) {
                int row = rbase + i * 16 + r;
                float v = acc[i][j][r] + b;
                if (EPI == 0) {
                    out_bf[(size_t)row * N + col] = f2bf(fmaxf(v, 0.0f));
                } else {
                    out_f[(size_t)row * N + col] = 1.0f / (1.0f + __expf(-v));
                }
            }
        }
    }
}

// ---------------- kv split-precision GEMM ----------------
// acc = Ah@Bh + Ah@Bl + Al@Bh  (~f32-accurate). N fixed 2048.
// col<1024 -> kout f32; col>=1024 -> gate_vg[row][col-1024] *= acc (v*gate, in place)
__global__ __launch_bounds__(256, 2) void gemm_kv_split_kernel(
    const unsigned short* __restrict__ Ah_,
    const unsigned short* __restrict__ Al_,
    const unsigned short* __restrict__ Bh_,
    const unsigned short* __restrict__ Bl_,
    float* __restrict__ gate_vg,
    float* __restrict__ kout,
    int M, int K)
{
    __shared__ unsigned short Ahs[128][32];
    __shared__ unsigned short Als[128][32];
    __shared__ unsigned short Bhs[128][32];
    __shared__ unsigned short Bls[128][32];
    const int N = 2048;
    int t = threadIdx.x;
    int lane = t & 63, w = t >> 6;
    int wm = w >> 1, wn = w & 1;
    int row0 = blockIdx.x * 128;
    int col0 = blockIdx.y * 128;

    f32x4_t acc[4][4];
#pragma unroll
    for (int i = 0; i < 4; ++i)
#pragma unroll
        for (int j = 0; j < 4; ++j) acc[i][j] = (f32x4_t)(0.0f);

    const unsigned short* Ahb = Ah_ + (size_t)row0 * K;
    const unsigned short* Alb = Al_ + (size_t)row0 * K;
    const unsigned short* Bhb = Bh_ + (size_t)col0 * K;
    const unsigned short* Blb = Bl_ + (size_t)col0 * K;

    for (int k0 = 0; k0 < K; k0 += 32) {
#pragma unroll
        for (int s = 0; s < 2; ++s) {
            int c = t + s * 256;
            int r = c >> 2, o8 = (c & 3) * 8;
            size_t g = (size_t)r * K + k0 + o8;
            *(int4*)(&Ahs[r][o8]) = *(const int4*)(Ahb + g);
            *(int4*)(&Als[r][o8]) = *(const int4*)(Alb + g);
            *(int4*)(&Bhs[r][o8]) = *(const int4*)(Bhb + g);
            *(int4*)(&Bls[r][o8]) = *(const int4*)(Blb + g);
        }
        __syncthreads();
        int kq = (lane >> 4) * 8;
        int mrow = wm * 64 + (lane & 15);
        int ncol = wn * 64 + (lane & 15);
        bf16x8_t ah[4], al[4], bh[4], bl[4];
#pragma unroll
        for (int i = 0; i < 4; ++i) {
            ah[i] = *(const bf16x8_t*)(&Ahs[mrow + i * 16][kq]);
            al[i] = *(const bf16x8_t*)(&Als[mrow + i * 16][kq]);
        }
#pragma unroll
        for (int j = 0; j < 4; ++j) {
            bh[j] = *(const bf16x8_t*)(&Bhs[ncol + j * 16][kq]);
            bl[j] = *(const bf16x8_t*)(&Bls[ncol + j * 16][kq]);
        }
#pragma unroll
        for (int i = 0; i < 4; ++i)
#pragma unroll
            for (int j = 0; j < 4; ++j) {
                acc[i][j] = __builtin_amdgcn_mfma_f32_16x16x32_bf16(ah[i], bh[j], acc[i][j], 0, 0, 0);
                acc[i][j] = __builtin_amdgcn_mfma_f32_16x16x32_bf16(ah[i], bl[j], acc[i][j], 0, 0, 0);
                acc[i][j] = __builtin_amdgcn_mfma_f32_16x16x32_bf16(al[i], bh[j], acc[i][j], 0, 0, 0);
            }
        __syncthreads();
    }

    int rbase = row0 + wm * 64 + ((lane >> 4) << 2);
    int cbase = col0 + wn * 64 + (lane & 15);
#pragma unroll
    for (int i = 0; i < 4; ++i) {
#pragma unroll
        for (int j = 0; j < 4; ++j) {
            int col = cbase + j * 16;
#pragma unroll
            for (int r = 0; r < 4; ++r) {
                int row = rbase + i * 16 + r;
                float v = acc[i][j][r];
                if (col < 1024) {
                    kout[(size_t)row * 1024 + col] = v;
                } else {
                    int e = col - 1024;
                    size_t idx = (size_t)row * 1024 + e;
                    gate_vg[idx] = v * gate_vg[idx];
                }
            }
        }
    }
    (void)N;
}

// ---------------- ctx partials (f32 in): part[p][bh][d][e] = sum_{n in chunk} k[n,d]*vg[n,e] ----------------
__global__ __launch_bounds__(256) void ctx_part_kernel(
    const float* __restrict__ kmat,
    const float* __restrict__ vmat,
    float* __restrict__ part)
{
    int bh = blockIdx.x & 63;
    int p  = blockIdx.x >> 6;   // 8 splits of N=4096
    int b = bh >> 4, h = bh & 15;
    int n0 = p * 512;
    __shared__ float ks[128][64];
    __shared__ float vs[128][64];
    int t = threadIdx.x;
    int dg = t & 15, eg = t >> 4;
    float acc[4][4];
#pragma unroll
    for (int i = 0; i < 4; ++i)
#pragma unroll
        for (int j = 0; j < 4; ++j) acc[i][j] = 0.0f;

    const float* kb = kmat + (size_t)b * 4096 * 1024 + h * 64;
    const float* vb = vmat + (size_t)b * 4096 * 1024 + h * 64;

    for (int c0 = 0; c0 < 512; c0 += 128) {
        __syncthreads();
#pragma unroll
        for (int s = 0; s < 8; ++s) {
            int ci = t + s * 256;                // 0..2047
            int r = ci >> 4, o4 = (ci & 15) * 4; // 16 x float4 per 256B row
            size_t g = (size_t)(n0 + c0 + r) * 1024 + o4;
            *(float4*)(&ks[r][o4]) = *(const float4*)(kb + g);
            *(float4*)(&vs[r][o4]) = *(const float4*)(vb + g);
        }
        __syncthreads();
#pragma unroll 4
        for (int n = 0; n < 128; ++n) {
            float4 k4 = *(const float4*)(&ks[n][dg * 4]);
            float4 v4 = *(const float4*)(&vs[n][eg * 4]);
            acc[0][0] += k4.x * v4.x; acc[0][1] += k4.x * v4.y; acc[0][2] += k4.x * v4.z; acc[0][3] += k4.x * v4.w;
            acc[1][0] += k4.y * v4.x; acc[1][1] += k4.y * v4.y; acc[1][2] += k4.y * v4.z; acc[1][3] += k4.y * v4.w;
            acc[2][0] += k4.z * v4.x; acc[2][1] += k4.z * v4.y; acc[2][2] += k4.z * v4.z; acc[2][3] += k4.z * v4.w;
            acc[3][0] += k4.w * v4.x; acc[3][1] += k4.w * v4.y; acc[3][2] += k4.w * v4.z; acc[3][3] += k4.w * v4.w;
        }
    }
    float* pp = part + ((size_t)(p * 64 + bh)) * 64 * 64;
#pragma unroll
    for (int i = 0; i < 4; ++i)
#pragma unroll
        for (int j = 0; j < 4; ++j)
            pp[(dg * 4 + i) * 64 + (eg * 4 + j)] = acc[i][j];
}

// ---------------- reduce partials + scale + column softmax (over d) ----------------
__global__ void softmax_ctx_kernel(const float* __restrict__ part, float* __restrict__ ctx) {
    int bh = blockIdx.x;
    int e = threadIdx.x;
    float col[64];
    float m = -1e30f;
#pragma unroll
    for (int d = 0; d < 64; ++d) {
        float s = 0.0f;
#pragma unroll
        for (int p = 0; p < 8; ++p)
            s += part[(((size_t)(p * 64 + bh)) * 64 + d) * 64 + e];
        s *= 0.125f;
        col[d] = s;
        m = fmaxf(m, s);
    }
    float sum = 0.0f;
#pragma unroll
    for (int d = 0; d < 64; ++d) {
        float v = __expf(col[d] - m);
        col[d] = v;
        sum += v;
    }
    float inv = 1.0f / sum;
#pragma unroll
    for (int d = 0; d < 64; ++d)
        ctx[((size_t)bh * 64 + d) * 64 + e] = col[d] * inv;
}

// ---------------- output: o[b,n,h*64+e] = sum_d x[b,n,h*64+d] * ctx[bh][d][e] ----------------
__global__ __launch_bounds__(256) void out_gemm_kernel(
    const float* __restrict__ x, const float* __restrict__ ctx, float* __restrict__ out)
{
    int id = blockIdx.x;
    int nc = id & 63;
    int h = (id >> 6) & 15;
    int b = id >> 10;
    size_t r0 = (size_t)b * 4096 + nc * 64;
    __shared__ float xs[64][65];
    __shared__ float cs[64][64];
    int t = threadIdx.x;
    for (int idx = t; idx < 4096; idx += 256) {
        int rr = idx >> 6, d = idx & 63;
        xs[rr][d] = x[(r0 + rr) * 1024 + h * 64 + d];
    }
    const float* cb = ctx + ((size_t)(b * 16 + h)) * 4096;
    for (int idx = t; idx < 4096; idx += 256) {
        cs[idx >> 6][idx & 63] = cb[idx];
    }
    __syncthreads();
    int eg = t & 15, nl = t >> 4;
    for (int rr = nl; rr < 64; rr += 16) {
        float a0 = 0.f, a1 = 0.f, a2 = 0.f, a3 = 0.f;
#pragma unroll
        for (int d = 0; d < 64; ++d) {
            float xv = xs[rr][d];
            float4 cv = *(const float4*)(&cs[d][eg * 4]);
            a0 += xv * cv.x; a1 += xv * cv.y; a2 += xv * cv.z; a3 += xv * cv.w;
        }
        float4 o = make_float4(a0, a1, a2, a3);
        *(float4*)(&out[(r0 + rr) * 1024 + h * 64 + eg * 4]) = o;
    }
}

// ---------------- host ----------------

extern "C" void kernel_launch(void* const* d_in, const int* in_sizes, int n_in,
                              void* d_out, int out_size, void* d_ws, size_t ws_size,
                              hipStream_t stream)
{
    (void)in_sizes; (void)n_in; (void)out_size; (void)ws_size;
    const float* x1   = (const float*)d_in[0];
    const float* x2   = (const float*)d_in[1];
    const float* Wkv1 = (const float*)d_in[2];
    const float* Wkv2 = (const float*)d_in[3];
    const float* g1w1 = (const float*)d_in[4];
    const float* g1b1 = (const float*)d_in[5];
    const float* g1w2 = (const float*)d_in[6];
    const float* g1b2 = (const float*)d_in[7];
    const float* g2w1 = (const float*)d_in[8];
    const float* g2b1 = (const float*)d_in[9];
    const float* g2w2 = (const float*)d_in[10];
    const float* g2b2 = (const float*)d_in[11];
    float* out = (float*)d_out;

    char* ws = (char*)d_ws;
    size_t off = 0;
    auto alloc = [&](size_t b) { void* p = ws + off; off += (b + 255) & ~(size_t)255; return p; };
    const size_t NTOK = 16384;
    unsigned short* xh    = (unsigned short*)alloc(NTOK * 1024 * 2);
    unsigned short* xl    = (unsigned short*)alloc(NTOK * 1024 * 2);
    unsigned short* wkv1h = (unsigned short*)alloc((size_t)2048 * 1024 * 2);
    unsigned short* wkv1l = (unsigned short*)alloc((size_t)2048 * 1024 * 2);
    unsigned short* wkv2h = (unsigned short*)alloc((size_t)2048 * 1024 * 2);
    unsigned short* wkv2l = (unsigned short*)alloc((size_t)2048 * 1024 * 2);
    unsigned short* g1w1t = (unsigned short*)alloc((size_t)1024 * 1024 * 2);
    unsigned short* g1w2t = (unsigned short*)alloc((size_t)1024 * 1024 * 2);
    unsigned short* g2w1t = (unsigned short*)alloc((size_t)1024 * 1024 * 2);
    unsigned short* g2w2t = (unsigned short*)alloc((size_t)1024 * 1024 * 2);
    unsigned short* hbuf  = (unsigned short*)alloc(NTOK * 1024 * 2);
    float* gate = (float*)alloc(NTOK * 1024 * 4);  // gate, then vg in place
    float* kbuf = (float*)alloc(NTOK * 1024 * 4);
    float* part = (float*)alloc((size_t)8 * 64 * 64 * 64 * 4);
    float* ctx1 = (float*)alloc((size_t)64 * 64 * 64 * 4);
    float* ctx2 = (float*)alloc((size_t)64 * 64 * 64 * 4);

    // weights
    cast_wt_split_kernel<<<dim3(64, 32), 256, 0, stream>>>(Wkv1, wkv1h, wkv1l, 1024, 2048);
    cast_wt_split_kernel<<<dim3(64, 32), 256, 0, stream>>>(Wkv2, wkv2h, wkv2l, 1024, 2048);
    cast_wt_kernel<<<dim3(32, 32), 256, 0, stream>>>(g1w1, g1w1t, 1024, 1024);
    cast_wt_kernel<<<dim3(32, 32), 256, 0, stream>>>(g1w2, g1w2t, 1024, 1024);
    cast_wt_kernel<<<dim3(32, 32), 256, 0, stream>>>(g2w1, g2w1t, 1024, 1024);
    cast_wt_kernel<<<dim3(32, 32), 256, 0, stream>>>(g2w2, g2w2t, 1024, 1024);

    // ---- stream 1 ----
    cast_x_split_kernel<<<2048, 256, 0, stream>>>(x1, xh, xl, (int)(NTOK * 1024 / 4));
    gemm_gate_kernel<0><<<dim3(128, 8), 256, 0, stream>>>(xh, g1w1t, g1b1, hbuf, nullptr, 16384, 1024, 1024);
    gemm_gate_kernel<1><<<dim3(128, 8), 256, 0, stream>>>(hbuf, g1w2t, g1b2, nullptr, gate, 16384, 1024, 1024);
    gemm_kv_split_kernel<<<dim3(128, 16), 256, 0, stream>>>(xh, xl, wkv1h, wkv1l, gate, kbuf, 16384, 1024);
    ctx_part_kernel<<<512, 256, 0, stream>>>(kbuf, gate, part);
    softmax_ctx_kernel<<<64, 64, 0, stream>>>(part, ctx1);

    // ---- stream 2 ----
    cast_x_split_kernel<<<2048, 256, 0, stream>>>(x2, xh, xl, (int)(NTOK * 1024 / 4));
    gemm_gate_kernel<0><<<dim3(128, 8), 256, 0, stream>>>(xh, g2w1t, g2b1, hbuf, nullptr, 16384, 1024, 1024);
    gemm_gate_kernel<1><<<dim3(128, 8), 256, 0, stream>>>(hbuf, g2w2t, g2b2, nullptr, gate, 16384, 1024, 1024);
    gemm_kv_split_kernel<<<dim3(128, 16), 256, 0, stream>>>(xh, xl, wkv2h, wkv2l, gate, kbuf, 16384, 1024);
    ctx_part_kernel<<<512, 256, 0, stream>>>(kbuf, gate, part);
    softmax_ctx_kernel<<<64, 64, 0, stream>>>(part, ctx2);

    // ---- outputs (cross: o1 uses ctx2, o2 uses ctx1) ----
    out_gemm_kernel<<<4096, 256, 0, stream>>>(x1, ctx2, out);
    out_gemm_kernel<<<4096, 256, 0, stream>>>(x2, ctx1, out + 16777216);
}